// Round 10
// baseline (126.719 us; speedup 1.0000x reference)
//
#include <hip/hip_runtime.h>
#include <hip/hip_bf16.h>

typedef _Float16 f16;
typedef _Float16 f16x2 __attribute__((ext_vector_type(2)));
typedef _Float16 f16x4 __attribute__((ext_vector_type(4)));
typedef _Float16 f16x8 __attribute__((ext_vector_type(8)));
typedef float f32x4 __attribute__((ext_vector_type(4)));

#define T_TOK 4096
#define V_N 32
#define H_N 256
#define LN_EPS_F 1e-5f

union U4 { f16x4 h; int i[2]; };

// ---------------- prep: W2,Wg [v][k][n] f32 -> [v][n][k] f16 ----------------
__global__ __launch_bounds__(256) void prep_transpose(
    const float* __restrict__ W2, const float* __restrict__ Wg,
    f16* __restrict__ W2t, f16* __restrict__ Wgt)
{
    __shared__ float tile[64][65];
    int bid = blockIdx.x;
    int w = bid >> 9;
    int rem = bid & 511;
    int v = rem >> 4;
    int kt = (rem >> 2) & 3;
    int nt = rem & 3;
    const float* src = w ? Wg : W2;
    f16* dst = w ? Wgt : W2t;
    const float* base = src + ((size_t)v * H_N + (size_t)kt * 64) * H_N + nt * 64;
    int tid = threadIdx.x;
    #pragma unroll
    for (int p = 0; p < 16; ++p) {
        int idx = p * 256 + tid;
        int r = idx >> 6, c = idx & 63;
        tile[r][c] = base[(size_t)r * H_N + c];
    }
    __syncthreads();
    f16* obase = dst + ((size_t)v * H_N + (size_t)nt * 64) * H_N + kt * 64;
    #pragma unroll
    for (int p = 0; p < 16; ++p) {
        int idx = p * 256 + tid;
        int r = idx >> 6, c = idx & 63;
        obase[(size_t)r * H_N + c] = (f16)tile[c][r];
    }
}

// ---------------- prep: W1,b1 f32 -> f16 ----------------
__global__ __launch_bounds__(256) void prep_w1(
    const float* __restrict__ W1, const float* __restrict__ b1,
    f16* __restrict__ W1h, f16* __restrict__ b1h)
{
    int i = blockIdx.x * 256 + threadIdx.x;   // grid 32 -> 8192
    W1h[i] = (f16)W1[i];
    b1h[i] = (f16)b1[i];
}

// ---------------- fused GRN: weights L2->registers, G=4 x nf=4, no weight-LDS ----
// grid 2048 = (v, mt64), 256 thr = 4 waves. Wave w owns ALL 64 block tokens
// (4 groups of 16) x n-quarter [w*64, w*64+64). Per step: 4 global af loads
// (2-step register prefetch rotation) feed 16 MFMAs. LDS only for H2^T exchange
// (granule-XOR swizzled) + LN/score cross-wave partials. Block reads each
// weight element exactly once from L2.
__global__ __launch_bounds__(256, 2) void fused_grn(
    const float* __restrict__ x,    // [T][V]
    const f16* __restrict__ W1h, const f16* __restrict__ b1h,   // [V][256]
    const f16* __restrict__ W2t, const float* __restrict__ b2,  // [V][n][k]
    const f16* __restrict__ Wgt, const float* __restrict__ bg,
    const float* __restrict__ gamma, const float* __restrict__ beta,
    const float* __restrict__ Wa, const float* __restrict__ ba,
    f16* __restrict__ VO,           // [V][T][H]
    float* __restrict__ scores)     // [T][V]
{
    __shared__ f16 H2L[64 * 256];        // 32 KB, granule-swizzled: sg = gidx^(tok&31)
    __shared__ float sqx[4][4][16][2];   // LN partials [wave][g][lo][s,q]
    __shared__ float spx[4][4][16];      // score partials

    int bid = blockIdx.x;
    int xcd = bid & 7, rr = bid >> 3;
    int v  = (xcd << 2) + (rr >> 6);     // 4 variables per XCD -> weights L2-local
    int mt = rr & 63;
    int tid = threadIdx.x;
    int w = tid >> 6, lane = tid & 63;
    int lo = lane & 15, hi = lane >> 4;
    int m0 = mt * 64;

    const f16* W2v = W2t + ((size_t)v << 16);
    const f16* Wgv = Wgt + ((size_t)v << 16);
    const f16* W1v = W1h + (v << 8);
    const f16* b1v = b1h + (v << 8);

    // per-nf af row base (halves): row = w*64 + nf*16 + lo, k-chunk hi; + s*32 per slice
    size_t rb0 = (size_t)(w * 64 + lo) * 256 + (hi << 3);

    // x splats per token group
    f16x8 x8[4];
    #pragma unroll
    for (int g = 0; g < 4; ++g) {
        f16 xh = (f16)x[(size_t)(m0 + g * 16 + lo) * V_N + v];
        x8[g] = f16x8{ xh, xh, xh, xh, xh, xh, xh, xh };
    }

    // 2-deep prefetch rotation (static indices only)
    f16x8 afr[2][4];
    f16x8 w8r[2], c8r[2];

    #pragma unroll
    for (int nf = 0; nf < 4; ++nf)
        afr[0][nf] = *(const f16x8*)&W2v[rb0 + (size_t)nf * 4096 + 0 * 32];
    w8r[0] = *(const f16x8*)&W1v[(0 << 5) + (hi << 3)];
    c8r[0] = *(const f16x8*)&b1v[(0 << 5) + (hi << 3)];
    #pragma unroll
    for (int nf = 0; nf < 4; ++nf)
        afr[1][nf] = *(const f16x8*)&W2v[rb0 + (size_t)nf * 4096 + 1 * 32];
    w8r[1] = *(const f16x8*)&W1v[(1 << 5) + (hi << 3)];
    c8r[1] = *(const f16x8*)&b1v[(1 << 5) + (hi << 3)];

    f32x4 acc[4][4] = {};   // [g][nf]: token = g*16+lo, n = w*64+nf*16+hi*4+r

    // ---- GEMM1: H2 = relu(x*W1+b1) @ W2, slices 0..7 ----
    #pragma unroll
    for (int s = 0; s < 8; ++s) {
        f16x8 af_[4];
        #pragma unroll
        for (int nf = 0; nf < 4; ++nf) af_[nf] = afr[s & 1][nf];
        f16x8 w8 = w8r[s & 1], c8 = c8r[s & 1];
        if (s < 6) {
            #pragma unroll
            for (int nf = 0; nf < 4; ++nf)
                afr[s & 1][nf] = *(const f16x8*)&W2v[rb0 + (size_t)nf * 4096 + (s + 2) * 32];
            w8r[s & 1] = *(const f16x8*)&W1v[((s + 2) << 5) + (hi << 3)];
            c8r[s & 1] = *(const f16x8*)&b1v[((s + 2) << 5) + (hi << 3)];
        } else {
            #pragma unroll
            for (int nf = 0; nf < 4; ++nf)
                afr[s & 1][nf] = *(const f16x8*)&Wgv[rb0 + (size_t)nf * 4096 + (s - 6) * 32];
        }
        #pragma unroll
        for (int g = 0; g < 4; ++g) {
            f16x8 hv = x8[g] * w8 + c8;
            #pragma unroll
            for (int j = 0; j < 8; ++j) hv[j] = hv[j] > (f16)0 ? hv[j] : (f16)0;
            #pragma unroll
            for (int nf = 0; nf < 4; ++nf)
                acc[g][nf] = __builtin_amdgcn_mfma_f32_16x16x32_f16(
                    af_[nf], hv, acc[g][nf], 0, 0, 0);
        }
    }

    // ---- H2 += b2 -> swizzled H2L (f16); zero acc ----
    #pragma unroll
    for (int g = 0; g < 4; ++g) {
        int tok = g * 16 + lo;
        #pragma unroll
        for (int nf = 0; nf < 4; ++nf) {
            int n0 = w * 64 + nf * 16 + (hi << 2);
            f32x4 b4 = *(const f32x4*)&b2[(v << 8) + n0];
            f32x4 h = acc[g][nf] + b4;
            U4 u; u.h = f16x4{ (f16)h[0], (f16)h[1], (f16)h[2], (f16)h[3] };
            int gidx = w * 8 + nf * 2 + (hi >> 1);
            int sg = gidx ^ (tok & 31);
            *(f16x4*)&H2L[tok * 256 + sg * 8 + (hi & 1) * 4] = u.h;
            acc[g][nf] = f32x4{ 0.f, 0.f, 0.f, 0.f };
        }
    }
    asm volatile("s_waitcnt lgkmcnt(0)" ::: "memory");
    __builtin_amdgcn_s_barrier();   // H2L complete; Wg reg-prefetches stay in flight

    // ---- GEMM2: acc = H2 @ Wg, slices 0..7; B-frag from swizzled H2L ----
    #pragma unroll
    for (int s = 0; s < 8; ++s) {
        f16x8 af_[4];
        #pragma unroll
        for (int nf = 0; nf < 4; ++nf) af_[nf] = afr[s & 1][nf];
        if (s < 6) {
            #pragma unroll
            for (int nf = 0; nf < 4; ++nf)
                afr[s & 1][nf] = *(const f16x8*)&Wgv[rb0 + (size_t)nf * 4096 + (s + 2) * 32];
        }
        #pragma unroll
        for (int g = 0; g < 4; ++g) {
            int tok = g * 16 + lo;
            int sg = ((s << 2) + hi) ^ (tok & 31);
            f16x8 bf = *(const f16x8*)&H2L[tok * 256 + sg * 8];
            #pragma unroll
            for (int nf = 0; nf < 4; ++nf)
                acc[g][nf] = __builtin_amdgcn_mfma_f32_16x16x32_f16(
                    af_[nf], bf, acc[g][nf], 0, 0, 0);
        }
    }

    // ---- gating (H2 re-read from H2L) + LN partials ----
    float sr[4] = {}, qr[4] = {};
    #pragma unroll
    for (int g = 0; g < 4; ++g) {
        int tok = g * 16 + lo;
        #pragma unroll
        for (int nf = 0; nf < 4; ++nf) {
            int n0 = w * 64 + nf * 16 + (hi << 2);
            f32x4 bgv = *(const f32x4*)&bg[(v << 8) + n0];
            int gidx = w * 8 + nf * 2 + (hi >> 1);
            int sg = gidx ^ (tok & 31);
            U4 u; u.h = *(const f16x4*)&H2L[tok * 256 + sg * 8 + (hi & 1) * 4];
            #pragma unroll
            for (int r = 0; r < 4; ++r) {
                float a = acc[g][nf][r] + bgv[r];
                float gg = 1.f / (1.f + __expf(-a));
                float val = gg * (float)u.h[r];
                acc[g][nf][r] = val;
                sr[g] += val; qr[g] += val * val;
            }
        }
    }
    #pragma unroll
    for (int g = 0; g < 4; ++g) {
        sr[g] += __shfl_xor(sr[g], 16); sr[g] += __shfl_xor(sr[g], 32);
        qr[g] += __shfl_xor(qr[g], 16); qr[g] += __shfl_xor(qr[g], 32);
    }
    if (hi == 0) {
        #pragma unroll
        for (int g = 0; g < 4; ++g) {
            sqx[w][g][lo][0] = sr[g];
            sqx[w][g][lo][1] = qr[g];
        }
    }
    __syncthreads();
    float mu[4], inv[4];
    #pragma unroll
    for (int g = 0; g < 4; ++g) {
        float st = sqx[0][g][lo][0] + sqx[1][g][lo][0] + sqx[2][g][lo][0] + sqx[3][g][lo][0];
        float qt = sqx[0][g][lo][1] + sqx[1][g][lo][1] + sqx[2][g][lo][1] + sqx[3][g][lo][1];
        mu[g] = st * (1.f / 256.f);
        float var = qt * (1.f / 256.f) - mu[g] * mu[g];
        inv[g] = rsqrtf(var + LN_EPS_F);
    }

    // ---- normalize + score partial + VO write ----
    float sp[4] = {};
    #pragma unroll
    for (int g = 0; g < 4; ++g) {
        f16* VOr = VO + ((size_t)v * T_TOK + m0 + g * 16 + lo) * H_N;
        #pragma unroll
        for (int nf = 0; nf < 4; ++nf) {
            int n0 = w * 64 + nf * 16 + (hi << 2);
            f32x4 gm = *(const f32x4*)&gamma[(v << 8) + n0];
            f32x4 bt = *(const f32x4*)&beta[(v << 8) + n0];
            f32x4 wa = *(const f32x4*)&Wa[n0];
            f16x4 ov;
            #pragma unroll
            for (int r = 0; r < 4; ++r) {
                float o = (acc[g][nf][r] - mu[g]) * inv[g] * gm[r] + bt[r];
                sp[g] += o * wa[r];
                ov[r] = (f16)o;
            }
            *(f16x4*)&VOr[n0] = ov;
        }
        sp[g] += __shfl_xor(sp[g], 16); sp[g] += __shfl_xor(sp[g], 32);
    }
    if (hi == 0) {
        #pragma unroll
        for (int g = 0; g < 4; ++g) spx[w][g][lo] = sp[g];
    }
    __syncthreads();
    if (w == 0 && hi == 0) {
        float bav = ba[0];
        #pragma unroll
        for (int g = 0; g < 4; ++g) {
            float t = spx[0][g][lo] + spx[1][g][lo] + spx[2][g][lo] + spx[3][g][lo] + bav;
            scores[(size_t)(m0 + g * 16 + lo) * V_N + v] = t;
        }
    }
}

// ---------------- softmax over V + pooled sum ----------------
__global__ __launch_bounds__(128) void pool(
    const f16* __restrict__ VO,       // [V][T][H]
    const float* __restrict__ scores, // [T][V]
    float* __restrict__ out)          // [T*H] vsn, then [T*V] attn
{
    int t = blockIdx.x, tid = threadIdx.x;
    __shared__ float sc[V_N];
    if (tid < V_N) sc[tid] = scores[t * V_N + tid];
    __syncthreads();
    float mx = -1e30f;
    #pragma unroll
    for (int v = 0; v < V_N; ++v) mx = fmaxf(mx, sc[v]);
    float e[V_N];
    float sum = 0.f;
    #pragma unroll
    for (int v = 0; v < V_N; ++v) { e[v] = __expf(sc[v] - mx); sum += e[v]; }
    float isum = 1.f / sum;
    float a0 = 0.f, a1 = 0.f;
    #pragma unroll
    for (int v = 0; v < V_N; ++v) {
        f16x2 vv = *(const f16x2*)&VO[((size_t)v * T_TOK + t) * H_N + tid * 2];
        float ww = e[v] * isum;
        a0 = fmaf((float)vv[0], ww, a0);
        a1 = fmaf((float)vv[1], ww, a1);
    }
    *(float2*)&out[(size_t)t * H_N + tid * 2] = make_float2(a0, a1);
    if (tid < V_N)
        out[(size_t)T_TOK * H_N + (size_t)t * V_N + tid] = e[tid] * isum;
}

extern "C" void kernel_launch(void* const* d_in, const int* in_sizes, int n_in,
                              void* d_out, int out_size, void* d_ws, size_t ws_size,
                              hipStream_t stream)
{
    const float* x     = (const float*)d_in[0];
    const float* W1    = (const float*)d_in[1];
    const float* b1    = (const float*)d_in[2];
    const float* W2    = (const float*)d_in[3];
    const float* b2    = (const float*)d_in[4];
    const float* Wg    = (const float*)d_in[5];
    const float* bg    = (const float*)d_in[6];
    const float* gamma = (const float*)d_in[7];
    const float* beta  = (const float*)d_in[8];
    const float* Wa    = (const float*)d_in[9];
    const float* ba    = (const float*)d_in[10];
    float* out = (float*)d_out;

    char* ws = (char*)d_ws;
    f16* W2t = (f16*)ws;                                        // 4 MB
    f16* Wgt = (f16*)(ws + ((size_t)4 << 20));                  // 4 MB
    f16* VO  = (f16*)(ws + ((size_t)8 << 20));                  // 64 MB
    float* scores = (float*)(ws + ((size_t)72 << 20));          // 512 KB
    f16* W1h = (f16*)(ws + ((size_t)72 << 20) + (512 << 10));   // 16 KB
    f16* b1h = (f16*)(ws + ((size_t)72 << 20) + (528 << 10));   // 16 KB

    prep_transpose<<<1024, 256, 0, stream>>>(W2, Wg, W2t, Wgt);
    prep_w1<<<32, 256, 0, stream>>>(W1, b1, W1h, b1h);
    fused_grn<<<2048, 256, 0, stream>>>(x, W1h, b1h, W2t, b2, Wgt, bg,
                                        gamma, beta, Wa, ba, VO, scores);
    pool<<<4096, 128, 0, stream>>>(VO, scores, out);
}

// Round 11
// 111.820 us; speedup vs baseline: 1.1332x; 1.1332x over previous
//
#include <hip/hip_runtime.h>
#include <hip/hip_bf16.h>

typedef _Float16 f16;
typedef _Float16 f16x2 __attribute__((ext_vector_type(2)));
typedef _Float16 f16x4 __attribute__((ext_vector_type(4)));
typedef _Float16 f16x8 __attribute__((ext_vector_type(8)));
typedef float f32x4 __attribute__((ext_vector_type(4)));

#define T_TOK 4096
#define V_N 32
#define H_N 256
#define LN_EPS_F 1e-5f

union U4 { f16x4 h; int i[2]; };

__device__ __forceinline__ void gload16(const f16* g, f16* l) {
    __builtin_amdgcn_global_load_lds(
        (const __attribute__((address_space(1))) void*)g,
        (__attribute__((address_space(3))) void*)l, 16, 0, 0);
}

// ---------------- prep: W2,Wg [v][k][n] f32 -> [v][n][k] f16 ----------------
__global__ __launch_bounds__(256) void prep_transpose(
    const float* __restrict__ W2, const float* __restrict__ Wg,
    f16* __restrict__ W2t, f16* __restrict__ Wgt)
{
    __shared__ float tile[64][65];
    int bid = blockIdx.x;
    int w = bid >> 9;
    int rem = bid & 511;
    int v = rem >> 4;
    int kt = (rem >> 2) & 3;
    int nt = rem & 3;
    const float* src = w ? Wg : W2;
    f16* dst = w ? Wgt : W2t;
    const float* base = src + ((size_t)v * H_N + (size_t)kt * 64) * H_N + nt * 64;
    int tid = threadIdx.x;
    #pragma unroll
    for (int p = 0; p < 16; ++p) {
        int idx = p * 256 + tid;
        int r = idx >> 6, c = idx & 63;
        tile[r][c] = base[(size_t)r * H_N + c];
    }
    __syncthreads();
    f16* obase = dst + ((size_t)v * H_N + (size_t)nt * 64) * H_N + kt * 64;
    #pragma unroll
    for (int p = 0; p < 16; ++p) {
        int idx = p * 256 + tid;
        int r = idx >> 6, c = idx & 63;
        obase[(size_t)r * H_N + c] = (f16)tile[c][r];
    }
}

// ---------------- prep: W1,b1 f32 -> f16 ----------------
__global__ __launch_bounds__(256) void prep_w1(
    const float* __restrict__ W1, const float* __restrict__ b1,
    f16* __restrict__ W1h, f16* __restrict__ b1h)
{
    int i = blockIdx.x * 256 + threadIdx.x;   // grid 32 -> 8192
    W1h[i] = (f16)W1[i];
    b1h[i] = (f16)b1[i];
}

// ---------------- fused GRN: barrier-minimal, wave-private staging ----------------
// grid 2048 = (v, mt64), 256 thr = 4 waves. Wave w owns all 64 tokens (G=4 groups
// of 16) x n-quarter [w*64,(w+1)*64). GEMM1: Wb triple-buffer (wave-private rows ->
// NO barriers, per-wave counted vmcnt only). H2L (32KB) overlays Wb after 1 barrier,
// granule-XOR swizzled (sg = g ^ 2*lo). GEMM2: af global->reg 2-deep rotation,
// bf from H2L -- barrier-free. 4 barriers total.
__global__ __launch_bounds__(256, 3) void fused_grn(
    const float* __restrict__ x,    // [T][V]
    const f16* __restrict__ W1h, const f16* __restrict__ b1h,   // [V][256]
    const f16* __restrict__ W2t, const float* __restrict__ b2,  // [V][n][k]
    const f16* __restrict__ Wgt, const float* __restrict__ bg,
    const float* __restrict__ gamma, const float* __restrict__ beta,
    const float* __restrict__ Wa, const float* __restrict__ ba,
    f16* __restrict__ VO,           // [V][T][H]
    float* __restrict__ scores)     // [T][V]
{
    __shared__ __align__(16) char pool_[52224];
    f16* Wb  = (f16*)pool_;                        // 3 x 8192 f16 (48 KB)
    f16* H2L = (f16*)pool_;                        // 32 KB overlay on Wb[0..1]
    float* sqx = (float*)(pool_ + 49152);          // [4][4][16][2]
    float* spx = (float*)(pool_ + 49152 + 2048);   // [4][4][16]

    int bid = blockIdx.x;
    int xcd = bid & 7, rr = bid >> 3;
    int v  = (xcd << 2) + (rr >> 6);
    int mt = rr & 63;
    int tid = threadIdx.x;
    int w = tid >> 6, lane = tid & 63;
    int lo = lane & 15, hi = lane >> 4;
    int m0 = mt * 64;

    const f16* W2v = W2t + ((size_t)v << 16);
    const f16* Wgv = Wgt + ((size_t)v << 16);
    const f16* W1v = W1h + (v << 8);
    const f16* b1v = b1h + (v << 8);

    // stage slice s of Wv into Wb[buf]: wave w stages ONLY its rows [w*64,(w+1)*64)
    // source chunk-swizzled c^(n&3) (verified r8); linear LDS dest.
    auto stageg = [&](const f16* Wv, int s, int buf) {
        int cs = (lane & 3) ^ ((lane >> 2) & 3);
        #pragma unroll
        for (int i = 0; i < 4; ++i) {
            int n = ((w * 4 + i) << 4) + (lane >> 2);
            gload16(Wv + ((size_t)n << 8) + (s << 5) + (cs << 3),
                    &Wb[buf * 8192 + ((w * 4 + i) << 9)]);
        }
    };

    stageg(W2v, 0, 0);
    stageg(W2v, 1, 1);

    f16x8 w8A = *(const f16x8*)&W1v[(0 << 5) + (hi << 3)];
    f16x8 c8A = *(const f16x8*)&b1v[(0 << 5) + (hi << 3)];
    f16x8 w8B = *(const f16x8*)&W1v[(1 << 5) + (hi << 3)];
    f16x8 c8B = *(const f16x8*)&b1v[(1 << 5) + (hi << 3)];

    f16x8 x8[4];
    #pragma unroll
    for (int g = 0; g < 4; ++g) {
        f16 xh = (f16)x[(size_t)(m0 + g * 16 + lo) * V_N + v];
        x8[g] = f16x8{ xh, xh, xh, xh, xh, xh, xh, xh };
    }

    f32x4 acc[4][4] = {};   // [g][nf]: token = m0+g*16+lo, n = w*64+nf*16+hi*4+r
    const int afbase = ((hi ^ (lo & 3)) << 3);
    const int rwb = (w * 64 + lo) << 5;

#define WAITV(N) asm volatile("s_waitcnt vmcnt(" #N ")" ::: "memory")

    // GEMM1 step S (uses W1 rotation slot W8/C8, Wb buf S%3); refills + stages S+2
#define G1STEP(W8, C8, S)                                                        \
    {                                                                            \
        f16x8 w8_ = W8, c8_ = C8;                                                \
        if (S < 6) {                                                             \
            stageg(W2v, S + 2, (S + 2) % 3);                                     \
            W8 = *(const f16x8*)&W1v[((S + 2) << 5) + (hi << 3)];                \
            C8 = *(const f16x8*)&b1v[((S + 2) << 5) + (hi << 3)];                \
        }                                                                        \
        f16x8 hv_[4];                                                            \
        _Pragma("unroll")                                                        \
        for (int g = 0; g < 4; ++g) {                                            \
            f16x8 t = x8[g] * w8_ + c8_;                                         \
            _Pragma("unroll")                                                    \
            for (int j = 0; j < 8; ++j) t[j] = t[j] > (f16)0 ? t[j] : (f16)0;    \
            hv_[g] = t;                                                          \
        }                                                                        \
        _Pragma("unroll")                                                        \
        for (int nf = 0; nf < 4; ++nf) {                                         \
            f16x8 af = *(const f16x8*)&Wb[(S % 3) * 8192 + rwb + (nf << 9) + afbase]; \
            _Pragma("unroll")                                                    \
            for (int g = 0; g < 4; ++g)                                          \
                acc[g][nf] = __builtin_amdgcn_mfma_f32_16x16x32_f16(             \
                    af, hv_[g], acc[g][nf], 0, 0, 0);                            \
        }                                                                        \
    }

    // ---- GEMM1: barrier-free (Wb rows are wave-private) ----
    WAITV(0);  G1STEP(w8A, c8A, 0)
               G1STEP(w8B, c8B, 1)
    WAITV(6);  G1STEP(w8A, c8A, 2)
    WAITV(6);  G1STEP(w8B, c8B, 3)
    WAITV(6);  G1STEP(w8A, c8A, 4)
    WAITV(6);  G1STEP(w8B, c8B, 5)
    WAITV(6);  G1STEP(w8A, c8A, 6)
    WAITV(0);  G1STEP(w8B, c8B, 7)

    __syncthreads();   // all waves done reading Wb -> safe to overlay H2L

    // ---- GEMM2 af prologue: slices 0,1 -> registers (land during H2L phase) ----
    f16x8 afA[4], afB[4];
    #pragma unroll
    for (int nf = 0; nf < 4; ++nf) {
        size_t rb = (size_t)((w * 64 + nf * 16 + lo) << 8) + (hi << 3);
        afA[nf] = *(const f16x8*)&Wgv[rb];
        afB[nf] = *(const f16x8*)&Wgv[rb + 32];
    }

    // ---- H2 += b2 -> swizzled H2L (granule sg = g ^ 2*lo); zero acc ----
    #pragma unroll
    for (int g = 0; g < 4; ++g) {
        int tok = g * 16 + lo;
        #pragma unroll
        for (int nf = 0; nf < 4; ++nf) {
            int n0 = w * 64 + nf * 16 + (hi << 2);
            f32x4 b4 = *(const f32x4*)&b2[(v << 8) + n0];
            f32x4 h = acc[g][nf] + b4;
            U4 u; u.h = f16x4{ (f16)h[0], (f16)h[1], (f16)h[2], (f16)h[3] };
            int gg = w * 16 + nf * 4 + hi;          // granule index n0>>2
            int sg = gg ^ (2 * lo);
            *(f16x4*)&H2L[tok * 256 + sg * 4] = u.h;
            acc[g][nf] = f32x4{ 0.f, 0.f, 0.f, 0.f };
        }
    }
    __syncthreads();   // H2L visible to all waves (drains af prefetch too)

    // GEMM2 step S: bf from H2L (swizzled), af from CUR regs; refill CUR slice S+2
#define G2STEP(CUR, S)                                                           \
    {                                                                            \
        _Pragma("unroll")                                                        \
        for (int g = 0; g < 4; ++g) {                                            \
            int tok = g * 16 + lo;                                               \
            int sgr = ((S) * 8 + hi * 2) ^ (2 * lo);                             \
            f16x8 bf = *(const f16x8*)&H2L[tok * 256 + sgr * 4];                 \
            _Pragma("unroll")                                                    \
            for (int nf = 0; nf < 4; ++nf)                                       \
                acc[g][nf] = __builtin_amdgcn_mfma_f32_16x16x32_f16(             \
                    CUR[nf], bf, acc[g][nf], 0, 0, 0);                           \
        }                                                                        \
        if (S < 6) {                                                             \
            _Pragma("unroll")                                                    \
            for (int nf = 0; nf < 4; ++nf) {                                     \
                size_t rb = (size_t)((w * 64 + nf * 16 + lo) << 8) + (hi << 3);  \
                CUR[nf] = *(const f16x8*)&Wgv[rb + ((S + 2) << 5)];              \
            }                                                                    \
        }                                                                        \
    }

    // ---- GEMM2: barrier-free ----
    G2STEP(afA, 0)
    G2STEP(afB, 1)
    G2STEP(afA, 2)
    G2STEP(afB, 3)
    G2STEP(afA, 4)
    G2STEP(afB, 5)
    G2STEP(afA, 6)
    G2STEP(afB, 7)

    // ---- gating (H2 re-read from H2L) + LN partials ----
    float sr[4] = {}, qr[4] = {};
    #pragma unroll
    for (int g = 0; g < 4; ++g) {
        int tok = g * 16 + lo;
        #pragma unroll
        for (int nf = 0; nf < 4; ++nf) {
            int n0 = w * 64 + nf * 16 + (hi << 2);
            f32x4 bgv = *(const f32x4*)&bg[(v << 8) + n0];
            int gg = w * 16 + nf * 4 + hi;
            int sg = gg ^ (2 * lo);
            U4 u; u.h = *(const f16x4*)&H2L[tok * 256 + sg * 4];
            #pragma unroll
            for (int r = 0; r < 4; ++r) {
                float a = acc[g][nf][r] + bgv[r];
                float gsig = 1.f / (1.f + __expf(-a));
                float val = gsig * (float)u.h[r];
                acc[g][nf][r] = val;
                sr[g] += val; qr[g] += val * val;
            }
        }
    }
    #pragma unroll
    for (int g = 0; g < 4; ++g) {
        sr[g] += __shfl_xor(sr[g], 16); sr[g] += __shfl_xor(sr[g], 32);
        qr[g] += __shfl_xor(qr[g], 16); qr[g] += __shfl_xor(qr[g], 32);
    }
    if (hi == 0) {
        #pragma unroll
        for (int g = 0; g < 4; ++g) {
            sqx[((w * 4 + g) * 16 + lo) * 2 + 0] = sr[g];
            sqx[((w * 4 + g) * 16 + lo) * 2 + 1] = qr[g];
        }
    }
    __syncthreads();
    float mu[4], inv[4];
    #pragma unroll
    for (int g = 0; g < 4; ++g) {
        float st = 0.f, qt = 0.f;
        #pragma unroll
        for (int ww = 0; ww < 4; ++ww) {
            st += sqx[((ww * 4 + g) * 16 + lo) * 2 + 0];
            qt += sqx[((ww * 4 + g) * 16 + lo) * 2 + 1];
        }
        mu[g] = st * (1.f / 256.f);
        float var = qt * (1.f / 256.f) - mu[g] * mu[g];
        inv[g] = rsqrtf(var + LN_EPS_F);
    }

    // ---- normalize + score partial + VO write ----
    float sp[4] = {};
    #pragma unroll
    for (int g = 0; g < 4; ++g) {
        f16* VOr = VO + ((size_t)v * T_TOK + m0 + g * 16 + lo) * H_N;
        #pragma unroll
        for (int nf = 0; nf < 4; ++nf) {
            int n0 = w * 64 + nf * 16 + (hi << 2);
            f32x4 gm = *(const f32x4*)&gamma[(v << 8) + n0];
            f32x4 bt = *(const f32x4*)&beta[(v << 8) + n0];
            f32x4 wa = *(const f32x4*)&Wa[n0];
            f16x4 ov;
            #pragma unroll
            for (int r = 0; r < 4; ++r) {
                float o = (acc[g][nf][r] - mu[g]) * inv[g] * gm[r] + bt[r];
                sp[g] += o * wa[r];
                ov[r] = (f16)o;
            }
            *(f16x4*)&VOr[n0] = ov;
        }
        sp[g] += __shfl_xor(sp[g], 16); sp[g] += __shfl_xor(sp[g], 32);
    }
    if (hi == 0) {
        #pragma unroll
        for (int g = 0; g < 4; ++g) spx[(w * 4 + g) * 16 + lo] = sp[g];
    }
    __syncthreads();
    if (w == 0 && hi == 0) {
        float bav = ba[0];
        #pragma unroll
        for (int g = 0; g < 4; ++g) {
            float t = spx[(0 * 4 + g) * 16 + lo] + spx[(1 * 4 + g) * 16 + lo]
                    + spx[(2 * 4 + g) * 16 + lo] + spx[(3 * 4 + g) * 16 + lo] + bav;
            scores[(size_t)(m0 + g * 16 + lo) * V_N + v] = t;
        }
    }
#undef G1STEP
#undef G2STEP
#undef WAITV
}

// ---------------- softmax over V + pooled sum ----------------
__global__ __launch_bounds__(128) void pool(
    const f16* __restrict__ VO,       // [V][T][H]
    const float* __restrict__ scores, // [T][V]
    float* __restrict__ out)          // [T*H] vsn, then [T*V] attn
{
    int t = blockIdx.x, tid = threadIdx.x;
    __shared__ float sc[V_N];
    if (tid < V_N) sc[tid] = scores[t * V_N + tid];
    __syncthreads();
    float mx = -1e30f;
    #pragma unroll
    for (int v = 0; v < V_N; ++v) mx = fmaxf(mx, sc[v]);
    float e[V_N];
    float sum = 0.f;
    #pragma unroll
    for (int v = 0; v < V_N; ++v) { e[v] = __expf(sc[v] - mx); sum += e[v]; }
    float isum = 1.f / sum;
    float a0 = 0.f, a1 = 0.f;
    #pragma unroll
    for (int v = 0; v < V_N; ++v) {
        f16x2 vv = *(const f16x2*)&VO[((size_t)v * T_TOK + t) * H_N + tid * 2];
        float ww = e[v] * isum;
        a0 = fmaf((float)vv[0], ww, a0);
        a1 = fmaf((float)vv[1], ww, a1);
    }
    *(float2*)&out[(size_t)t * H_N + tid * 2] = make_float2(a0, a1);
    if (tid < V_N)
        out[(size_t)T_TOK * H_N + (size_t)t * V_N + tid] = e[tid] * isum;
}

extern "C" void kernel_launch(void* const* d_in, const int* in_sizes, int n_in,
                              void* d_out, int out_size, void* d_ws, size_t ws_size,
                              hipStream_t stream)
{
    const float* x     = (const float*)d_in[0];
    const float* W1    = (const float*)d_in[1];
    const float* b1    = (const float*)d_in[2];
    const float* W2    = (const float*)d_in[3];
    const float* b2    = (const float*)d_in[4];
    const float* Wg    = (const float*)d_in[5];
    const float* bg    = (const float*)d_in[6];
    const float* gamma = (const float*)d_in[7];
    const float* beta  = (const float*)d_in[8];
    const float* Wa    = (const float*)d_in[9];
    const float* ba    = (const float*)d_in[10];
    float* out = (float*)d_out;

    char* ws = (char*)d_ws;
    f16* W2t = (f16*)ws;                                        // 4 MB
    f16* Wgt = (f16*)(ws + ((size_t)4 << 20));                  // 4 MB
    f16* VO  = (f16*)(ws + ((size_t)8 << 20));                  // 64 MB
    float* scores = (float*)(ws + ((size_t)72 << 20));          // 512 KB
    f16* W1h = (f16*)(ws + ((size_t)72 << 20) + (512 << 10));   // 16 KB
    f16* b1h = (f16*)(ws + ((size_t)72 << 20) + (528 << 10));   // 16 KB

    prep_transpose<<<1024, 256, 0, stream>>>(W2, Wg, W2t, Wgt);
    prep_w1<<<32, 256, 0, stream>>>(W1, b1, W1h, b1h);
    fused_grn<<<2048, 256, 0, stream>>>(x, W1h, b1h, W2t, b2, Wgt, bg,
                                        gamma, beta, Wa, ba, VO, scores);
    pool<<<4096, 128, 0, stream>>>(VO, scores, out);
}